// Round 4
// baseline (223.044 us; speedup 1.0000x reference)
//
#include <hip/hip_runtime.h>

// YOLO layer: (64, 3*85, 44, 44) -> (64, 3*44*44, 85), fp32.
// R3 counters: kernel 79 us, HBM 2.4 TB/s (30%), VALUBusy 27%, Occ 62%,
// LDS_BANK_CONFLICT 4.86M. FETCH 61.8 MB < 126 MB input => NT stores are
// keeping input L3-resident (R0 theory confirmed). Nothing saturated =>
// latency-bound; biggest identified cost: phase-2 gather at stride-89 is an
// 8-way bank conflict x4 scalar ds_reads, wrap conditional blocks b128.
// R4: packed stride-85 LDS = exact output image. Phase 2 becomes contiguous
// ds_read_b128 + NT float4 store (conflict-free, 4x fewer LDS instrs).
// Phase-1b transposed writes at stride 85: bank=(20q+85j+c)%32 -> 2-way max
// (free). LDS 22784->21760 B -> 7 blocks/CU cap.

#define BSZ      64
#define NA       3
#define NC       80
#define GRID     44
#define SPATIAL  (GRID * GRID)       // 1936
#define CH       (5 + NC)            // 85
#define TILE     64
#define TILES_PER_BA ((SPATIAL + TILE - 1) / TILE)   // 31 (last tile: 16 valid)
#define NF       (CH * (TILE / 4))   // 1360 float4 loads per block
#define NITER    ((NF + 255) / 256)  // 6
#define STRIDE_F 8.0f                // 352 / 44; cancels /STRIDE in scaled anchors
#define NXCD     8
#define NWG      (BSZ * NA * TILES_PER_BA)   // 5952 (divisible by 8)
#define CHUNK    (NWG / NXCD)                // 744

typedef float vfloat4 __attribute__((ext_vector_type(4)));

__device__ __forceinline__ float sigf(float x) {
    return 1.0f / (1.0f + __expf(-x));
}

__global__ __launch_bounds__(256, 4)
void yolo_kernel(const float* __restrict__ in, float* __restrict__ out) {
    __shared__ float tile[TILE * CH];     // packed [s][c], 21760 B -> 7 blocks/CU

    // XCD-chunked swizzle: launch-id % 8 picks the XCD (round-robin dispatch);
    // give that XCD a contiguous chunk of work-items. Bijective since NWG%8==0.
    const int bid0 = blockIdx.x;
    const int bid  = (bid0 % NXCD) * CHUNK + bid0 / NXCD;

    const int t   = bid % TILES_PER_BA;
    const int ba  = bid / TILES_PER_BA;   // b*NA + a
    const int a   = ba % NA;

    const int s0    = t * TILE;
    const int valid = min(TILE, SPATIAL - s0);   // 64 or 16; always mult of 4

    const float aw = (a == 0) ? 10.0f : (a == 1) ? 16.0f : 33.0f;
    const float ah = (a == 0) ? 13.0f : (a == 1) ? 30.0f : 23.0f;

    const int tid = threadIdx.x;
    const float* inbase = in + (size_t)ba * CH * SPATIAL + s0;

    // ---- phase 1a: issue ALL global loads first (bytes in flight) ----
    float4 v[NITER];
    #pragma unroll
    for (int i = 0; i < NITER; ++i) {
        int f = tid + i * 256;            // f -> (channel c, spatial quad q)
        int c = f >> 4, q = f & 15;
        if (f < NF && q * 4 < valid)
            v[i] = *(const float4*)(inbase + (size_t)c * SPATIAL + q * 4);
    }

    // ---- phase 1b: transform + LDS transpose write (packed [s][c]) ----
    #pragma unroll
    for (int i = 0; i < NITER; ++i) {
        int f = tid + i * 256;
        int c = f >> 4, q = f & 15;
        if (f >= NF || q * 4 >= valid) continue;
        float r[4] = {v[i].x, v[i].y, v[i].z, v[i].w};
        #pragma unroll
        for (int j = 0; j < 4; ++j) {
            int   sl = q * 4 + j;         // local spatial
            int   gs = s0 + sl;           // global spatial
            float x  = r[j];
            float o;
            if (c == 0)      o = (sigf(x) + (float)(gs % GRID)) * STRIDE_F;
            else if (c == 1) o = (sigf(x) + (float)(gs / GRID)) * STRIDE_F;
            else if (c == 2) o = __expf(x) * aw;
            else if (c == 3) o = __expf(x) * ah;
            else             o = sigf(x);  // conf + 80 classes
            tile[sl * CH + c] = o;        // 2-way max bank aliasing (free)
        }
    }
    __syncthreads();

    // ---- phase 2: contiguous ds_read_b128 + NT float4 store ----
    // LDS is the exact output image of this block: copy valid*CH floats.
    const size_t obase = ((size_t)ba * SPATIAL + s0) * CH;  // 16B-aligned
    const int total = valid * CH;         // 5440 or 1360, both mult of 4
    for (int k4 = tid * 4; k4 < total; k4 += 1024) {
        vfloat4 w = *(const vfloat4*)(tile + k4);   // lane-contiguous: no conflicts
        __builtin_nontemporal_store(w, (vfloat4*)(out + obase + k4));
    }
}

extern "C" void kernel_launch(void* const* d_in, const int* in_sizes, int n_in,
                              void* d_out, int out_size, void* d_ws, size_t ws_size,
                              hipStream_t stream) {
    const float* in = (const float*)d_in[0];
    float* out = (float*)d_out;
    yolo_kernel<<<NWG, 256, 0, stream>>>(in, out);
}